// Round 2
// baseline (619.574 us; speedup 1.0000x reference)
//
#include <hip/hip_runtime.h>

// GraphVAE forward, Agg = D^-1/2 (A+I) D^-1/2 via CSR (counting sort by dst).
// Key algebra: all agg inputs are pre-scaled rows Hs[r] = dinv[r]*H[r], so
//   agg[i] = dinv[i] * ( sum_{e:dst=i} Hs[src_e] + Hs[i] )
// and the inner gather loop is pure {index, row-load, add}.

static __host__ __device__ inline size_t ws_align(size_t x) { return (x + 255) & ~size_t(255); }

// ---------------- degree / dinv ----------------
__global__ void k_deg(const int* __restrict__ dst, int E, int* __restrict__ deg) {
    int e = blockIdx.x * blockDim.x + threadIdx.x;
    if (e < E) atomicAdd(&deg[dst[e]], 1);
}

__global__ void k_dinv(const int* __restrict__ deg, int N, float* __restrict__ dinv) {
    int i = blockIdx.x * blockDim.x + threadIdx.x;
    if (i < N) dinv[i] = rsqrtf((float)(deg[i] + 1));  // +1 self-loop
}

// ---------------- scan (3-kernel exclusive prefix sum over deg) ----------------
__global__ void k_scan_partial(const int* __restrict__ deg, int N, int* __restrict__ part) {
    __shared__ int s[256];
    int t = threadIdx.x;
    int i = blockIdx.x * 256 + t;
    s[t] = (i < N) ? deg[i] : 0;
    __syncthreads();
    for (int off = 128; off > 0; off >>= 1) {
        if (t < off) s[t] += s[t + off];
        __syncthreads();
    }
    if (t == 0) part[blockIdx.x] = s[0];
}

__global__ void k_scan_top(const int* __restrict__ part, int nb, int* __restrict__ scanned) {
    __shared__ int s[512];
    int t = threadIdx.x;
    int v = (t < nb) ? part[t] : 0;
    s[t] = v;
    __syncthreads();
    for (int off = 1; off < 512; off <<= 1) {
        int x = 0;
        if (t >= off) x = s[t - off];
        __syncthreads();
        s[t] += x;
        __syncthreads();
    }
    if (t < nb) scanned[t] = s[t] - v;  // exclusive
}

__global__ void k_scan_down(const int* __restrict__ deg, int N, int E,
                            const int* __restrict__ scanned, int* __restrict__ offsets) {
    __shared__ int s[256];
    int t = threadIdx.x;
    int i = blockIdx.x * 256 + t;
    int v = (i < N) ? deg[i] : 0;
    s[t] = v;
    __syncthreads();
    for (int off = 1; off < 256; off <<= 1) {
        int x = 0;
        if (t >= off) x = s[t - off];
        __syncthreads();
        s[t] += x;
        __syncthreads();
    }
    if (i < N) offsets[i] = scanned[blockIdx.x] + s[t] - v;  // exclusive
    if (blockIdx.x == 0 && t == 0) offsets[N] = E;
}

// ---------------- CSR scatter (cursor pre-initialized to offsets) ----------------
__global__ void k_scatter(const int* __restrict__ src, const int* __restrict__ dst, int E,
                          int* __restrict__ cursor, int* __restrict__ src_sorted) {
    int e = blockIdx.x * blockDim.x + threadIdx.x;
    if (e < E) {
        int slot = atomicAdd(&cursor[dst[e]], 1);
        src_sorted[slot] = src[e];
    }
}

// ---------------- GEMM: C[N,64] = dinv[r] * (X[N,128] @ W[128,64])[r] ----------------
__global__ __launch_bounds__(256) void k_gemm_in(const float* __restrict__ X,
                                                 const float* __restrict__ W,
                                                 const float* __restrict__ dinv, int N,
                                                 float* __restrict__ C) {
    __shared__ float Ws[128 * 64];
    __shared__ float Xs[16][128];
    int t = threadIdx.x;
    const float4* W4 = (const float4*)W;
    float4* Ws4 = (float4*)Ws;
#pragma unroll
    for (int j = 0; j < 8; j++) Ws4[t + 256 * j] = W4[t + 256 * j];
    int row0 = blockIdx.x * 16;
    const float4* X4 = (const float4*)(X + (size_t)row0 * 128);
    float4* Xs4 = (float4*)&Xs[0][0];
#pragma unroll
    for (int j = 0; j < 2; j++) Xs4[t + 256 * j] = X4[t + 256 * j];
    __syncthreads();
    int r = t >> 4;          // 16 rows
    int c0 = (t & 15) * 4;   // 4 cols per thread
    float a0 = 0.f, a1 = 0.f, a2 = 0.f, a3 = 0.f;
#pragma unroll 4
    for (int k = 0; k < 128; k++) {
        float xv = Xs[r][k];
        float4 w = *(const float4*)&Ws[k * 64 + c0];
        a0 += xv * w.x; a1 += xv * w.y; a2 += xv * w.z; a3 += xv * w.w;
    }
    float dv = dinv[row0 + r];
    float4 out = {a0 * dv, a1 * dv, a2 * dv, a3 * dv};
    *(float4*)(C + (size_t)(row0 + r) * 64 + c0) = out;
}

// ---------------- Aggregation over pre-scaled rows ----------------
// FIRST: out = dinv * relu(dinv*(sum) + b)   (scaled for next agg pass)
// else : out = dinv * (sum)                  (this IS agg(h), feeds mu/lv GEMMs)
template <bool FIRST>
__global__ __launch_bounds__(256) void k_agg(const float* __restrict__ Hs,
                                             const float* __restrict__ dinv,
                                             const int* __restrict__ offsets,
                                             const int* __restrict__ src_sorted,
                                             const float* __restrict__ bias, int N,
                                             float* __restrict__ out) {
    int node = blockIdx.x * 4 + (threadIdx.x >> 6);  // one wave per node
    int lane = threadIdx.x & 63;                     // lane = feature
    if (node >= N) return;
    float dv = dinv[node];
    int beg = offsets[node], end = offsets[node + 1];
    int nu = __builtin_amdgcn_readfirstlane(node);
    float acc = Hs[(size_t)nu * 64 + lane];  // self-loop row
    float acc2 = 0.f;
    int j = beg;
    for (; j + 4 <= end; j += 4) {
        int s0 = __builtin_amdgcn_readfirstlane(src_sorted[j + 0]);
        int s1 = __builtin_amdgcn_readfirstlane(src_sorted[j + 1]);
        int s2 = __builtin_amdgcn_readfirstlane(src_sorted[j + 2]);
        int s3 = __builtin_amdgcn_readfirstlane(src_sorted[j + 3]);
        float h0 = Hs[(size_t)s0 * 64 + lane];
        float h1 = Hs[(size_t)s1 * 64 + lane];
        float h2 = Hs[(size_t)s2 * 64 + lane];
        float h3 = Hs[(size_t)s3 * 64 + lane];
        acc += h0 + h1;
        acc2 += h2 + h3;
    }
    for (; j < end; j++) {
        int s = __builtin_amdgcn_readfirstlane(src_sorted[j]);
        acc += Hs[(size_t)s * 64 + lane];
    }
    acc += acc2;
    float v;
    if (FIRST) {
        v = dv * acc + bias[lane];
        v = fmaxf(v, 0.f) * dv;  // pre-scale for second agg pass
    } else {
        v = dv * acc;
    }
    out[(size_t)node * 64 + lane] = v;
}

// ---------------- Fused mu/logvar/z ----------------
__global__ __launch_bounds__(256) void k_muvz(const float* __restrict__ AGG,
                                              const float* __restrict__ Wmu,
                                              const float* __restrict__ bmu,
                                              const float* __restrict__ Wlv,
                                              const float* __restrict__ blv,
                                              const float* __restrict__ EPS, int N,
                                              float* __restrict__ mu_out,
                                              float* __restrict__ lv_out,
                                              float* __restrict__ z_out) {
    __shared__ float Wm[64 * 64];
    __shared__ float Wl[64 * 64];
    __shared__ float As[16][64];
    int t = threadIdx.x;
#pragma unroll
    for (int j = 0; j < 4; j++) {
        ((float4*)Wm)[t + 256 * j] = ((const float4*)Wmu)[t + 256 * j];
        ((float4*)Wl)[t + 256 * j] = ((const float4*)Wlv)[t + 256 * j];
    }
    int row0 = blockIdx.x * 16;
    ((float4*)&As[0][0])[t] = ((const float4*)(AGG + (size_t)row0 * 64))[t];
    __syncthreads();
    int r = t >> 4;
    int c0 = (t & 15) * 4;
    float m0 = 0.f, m1 = 0.f, m2 = 0.f, m3 = 0.f;
    float l0 = 0.f, l1 = 0.f, l2 = 0.f, l3 = 0.f;
#pragma unroll 4
    for (int k = 0; k < 64; k++) {
        float a = As[r][k];
        float4 wm = *(const float4*)&Wm[k * 64 + c0];
        float4 wl = *(const float4*)&Wl[k * 64 + c0];
        m0 += a * wm.x; m1 += a * wm.y; m2 += a * wm.z; m3 += a * wm.w;
        l0 += a * wl.x; l1 += a * wl.y; l2 += a * wl.z; l3 += a * wl.w;
    }
    size_t base = (size_t)(row0 + r) * 64 + c0;
    float4 bm = *(const float4*)&bmu[c0];
    float4 bl = *(const float4*)&blv[c0];
    float4 ep = *(const float4*)&EPS[base];
    m0 += bm.x; m1 += bm.y; m2 += bm.z; m3 += bm.w;
    l0 += bl.x; l1 += bl.y; l2 += bl.z; l3 += bl.w;
    float z0 = m0 + ep.x * expf(l0);
    float z1 = m1 + ep.y * expf(l1);
    float z2 = m2 + ep.z * expf(l2);
    float z3 = m3 + ep.w * expf(l3);
    *(float4*)&mu_out[base] = {m0, m1, m2, m3};
    *(float4*)&lv_out[base] = {l0, l1, l2, l3};
    *(float4*)&z_out[base] = {z0, z1, z2, z3};
}

// ---------------- Decoder: recon = sigmoid(Z[N,64] @ Wdec[64,128] + bdec) ----------------
__global__ __launch_bounds__(256) void k_dec(const float* __restrict__ Z,
                                             const float* __restrict__ Wdec,
                                             const float* __restrict__ bdec, int N,
                                             float* __restrict__ recon) {
    __shared__ float Ws[64 * 128];
    __shared__ float Zs[16][64];
    int t = threadIdx.x;
#pragma unroll
    for (int j = 0; j < 8; j++)
        ((float4*)Ws)[t + 256 * j] = ((const float4*)Wdec)[t + 256 * j];
    int row0 = blockIdx.x * 16;
    ((float4*)&Zs[0][0])[t] = ((const float4*)(Z + (size_t)row0 * 64))[t];
    __syncthreads();
    int r = t >> 4;
    int c0 = (t & 15) * 8;  // 8 cols per thread
    float a[8] = {0.f, 0.f, 0.f, 0.f, 0.f, 0.f, 0.f, 0.f};
#pragma unroll 4
    for (int k = 0; k < 64; k++) {
        float zv = Zs[r][k];
        float4 w0 = *(const float4*)&Ws[k * 128 + c0];
        float4 w1 = *(const float4*)&Ws[k * 128 + c0 + 4];
        a[0] += zv * w0.x; a[1] += zv * w0.y; a[2] += zv * w0.z; a[3] += zv * w0.w;
        a[4] += zv * w1.x; a[5] += zv * w1.y; a[6] += zv * w1.z; a[7] += zv * w1.w;
    }
    size_t base = (size_t)(row0 + r) * 128 + c0;
    float4 b0 = *(const float4*)&bdec[c0];
    float4 b1 = *(const float4*)&bdec[c0 + 4];
    float v0 = a[0] + b0.x, v1 = a[1] + b0.y, v2 = a[2] + b0.z, v3 = a[3] + b0.w;
    float v4 = a[4] + b1.x, v5 = a[5] + b1.y, v6 = a[6] + b1.z, v7 = a[7] + b1.w;
    float4 o0 = {1.f / (1.f + expf(-v0)), 1.f / (1.f + expf(-v1)),
                 1.f / (1.f + expf(-v2)), 1.f / (1.f + expf(-v3))};
    float4 o1 = {1.f / (1.f + expf(-v4)), 1.f / (1.f + expf(-v5)),
                 1.f / (1.f + expf(-v6)), 1.f / (1.f + expf(-v7))};
    *(float4*)&recon[base] = o0;
    *(float4*)&recon[base + 4] = o1;
}

extern "C" void kernel_launch(void* const* d_in, const int* in_sizes, int n_in,
                              void* d_out, int out_size, void* d_ws, size_t ws_size,
                              hipStream_t stream) {
    const float* x = (const float*)d_in[0];
    const int* edge_index = (const int*)d_in[1];
    const float* eps = (const float*)d_in[2];
    const float* W1 = (const float*)d_in[3];
    const float* b1 = (const float*)d_in[4];
    const float* Wmu = (const float*)d_in[5];
    const float* bmu = (const float*)d_in[6];
    const float* Wlv = (const float*)d_in[7];
    const float* blv = (const float*)d_in[8];
    const float* Wdec = (const float*)d_in[9];
    const float* bdec = (const float*)d_in[10];

    int N = in_sizes[0] / 128;
    int E = in_sizes[1] / 2;
    const int* src = edge_index;       // edge_index[0]
    const int* dst = edge_index + E;   // edge_index[1]

    float* recon = (float*)d_out;                      // [N,128]
    float* mu_out = (float*)d_out + (size_t)N * 128;   // [N,64]
    float* lv_out = mu_out + (size_t)N * 64;           // [N,64]

    // workspace layout
    char* p = (char*)d_ws;
    auto alloc = [&](size_t bytes) { char* r = p; p += ws_align(bytes); return r; };
    int nb = (N + 255) / 256;
    int* deg = (int*)alloc((size_t)N * 4);
    float* dinv = (float*)alloc((size_t)N * 4);
    int* offsets = (int*)alloc((size_t)(N + 1) * 4);
    int* cursor = (int*)alloc((size_t)N * 4);
    int* part = (int*)alloc((size_t)nb * 4);
    int* scanned = (int*)alloc((size_t)nb * 4);
    int* src_sorted = (int*)alloc((size_t)E * 4);
    float* bufA = (float*)alloc((size_t)N * 64 * 4);  // dinv*(x@W1), then agg(h)
    float* bufB = (float*)alloc((size_t)N * 64 * 4);  // dinv*h, then z

    hipMemsetAsync(deg, 0, (size_t)N * 4, stream);

    const int tpb = 256;
    k_deg<<<(E + tpb - 1) / tpb, tpb, 0, stream>>>(dst, E, deg);
    k_dinv<<<(N + tpb - 1) / tpb, tpb, 0, stream>>>(deg, N, dinv);
    k_scan_partial<<<nb, 256, 0, stream>>>(deg, N, part);
    k_scan_top<<<1, 512, 0, stream>>>(part, nb, scanned);  // nb=391 <= 512
    k_scan_down<<<nb, 256, 0, stream>>>(deg, N, E, scanned, offsets);
    hipMemcpyAsync(cursor, offsets, (size_t)N * 4, hipMemcpyDeviceToDevice, stream);
    k_scatter<<<(E + tpb - 1) / tpb, tpb, 0, stream>>>(src, dst, E, cursor, src_sorted);

    k_gemm_in<<<N / 16, 256, 0, stream>>>(x, W1, dinv, N, bufA);  // dinv*(x@W1)
    k_agg<true><<<(N + 3) / 4, 256, 0, stream>>>(bufA, dinv, offsets, src_sorted, b1, N, bufB);     // dinv*h
    k_agg<false><<<(N + 3) / 4, 256, 0, stream>>>(bufB, dinv, offsets, src_sorted, nullptr, N, bufA); // agg(h)
    k_muvz<<<N / 16, 256, 0, stream>>>(bufA, Wmu, bmu, Wlv, blv, eps, N, mu_out, lv_out, bufB);
    k_dec<<<N / 16, 256, 0, stream>>>(bufB, Wdec, bdec, N, recon);
}